// Round 7
// baseline (429.607 us; speedup 1.0000x reference)
//
#include <hip/hip_runtime.h>
#include <math.h>

namespace {

constexpr int B_ = 4, N_ = 4, C_ = 64, H_ = 128, W_ = 128;
constexpr int HW_ = H_ * W_;

// out[:, 4] = ref
__global__ __launch_bounds__(256) void copyref_kernel(const float* __restrict__ ref,
                                                      float* __restrict__ out) {
    int t = blockIdx.x * 256 + threadIdx.x;      // one float4 per thread
    int f = t * 4;
    int b = f / (C_ * HW_);
    int within = f - b * (C_ * HW_);
    float4 v = *reinterpret_cast<const float4*>(ref + (size_t)b * C_ * HW_ + within);
    *reinterpret_cast<float4*>(out + (size_t)(b * 5 + N_) * C_ * HW_ + within) = v;
}

// Main kernel: lane-quad C-split (PROVEN no-spill shape), 2 pixels per thread.
//   thread -> (pixel-pair, channel-chunk q of 16 channels); q = tid & 3 so the
//   4 partial reducers are adjacent lanes (width-4 shfl_xor butterfly, 2 steps).
//   Per-thread accumulator state: 9*2 + 3*4 + 2 = 32 floats (vs 94 in round 3).
//   block = 256 threads = 64 pixel-pairs = 1 row; grid = B*N*H = 2048 blocks.
//   XCD-swizzled: image bi -> XCD bi>>1 (2 images per XCD, same b shares ref).
__global__ __launch_bounds__(256, 4) void localcorr_kernel(const float* __restrict__ nbrs,
                                                           const float* __restrict__ ref,
                                                           float* __restrict__ out) {
    const int s = blockIdx.x;            // 0..2047
    const int j = s >> 3;                // 0..255
    const int bi = (s & 7) * 2 + (j >> 7);
    const int y = j & 127;
    const int i = bi & 3;
    const int b = bi >> 2;
    const int tid = (int)threadIdx.x;    // 0..255
    const int q = tid & 3;               // channel chunk (16 channels each)
    const int g = tid >> 2;              // pixel pair 0..63
    const int xb = g * 2;
    const int c0 = q * 16;

    // reflect-pad (np 'reflect', pad=1): idx -1 -> 1, idx W -> W-2
    const int ym1 = (y == 0) ? 1 : y - 1;
    const int yp1 = (y == H_ - 1) ? H_ - 2 : y + 1;
    const int xm1 = (xb == 0) ? 1 : xb - 1;
    const int xp2 = (xb + 2 == W_) ? W_ - 2 : xb + 2;

    const int ro0 = ym1 * W_, ro1 = y * W_, ro2 = yp1 * W_;

    const float* __restrict__ nb = nbrs + (size_t)(b * N_ + i) * C_ * HW_;
    const float* __restrict__ rp = ref + (size_t)b * C_ * HW_ + y * W_ + xb;

    float dot[9][2];     // partial dots over this thread's 16 channels
    float nrm2[3][4];    // partial sq-norms, 3 rows x 4 cols (xb-1 .. xb+2)
    float ref2[2];       // partial ref sq-norms
#pragma unroll
    for (int k = 0; k < 9; ++k) { dot[k][0] = 0.f; dot[k][1] = 0.f; }
#pragma unroll
    for (int r = 0; r < 3; ++r)
#pragma unroll
        for (int m = 0; m < 4; ++m) nrm2[r][m] = 0.f;
    ref2[0] = 0.f; ref2[1] = 0.f;

    // ---- pass 1 over this thread's channels: raw dots + squared norms ----
    for (int cc = 0; cc < 16; ++cc) {
        const int c = c0 + cc;
        const float* pc = nb + c * HW_;
        const float2 rv = *reinterpret_cast<const float2*>(rp + c * HW_);
        const float r2[2] = {rv.x, rv.y};
        ref2[0] += r2[0] * r2[0];
        ref2[1] += r2[1] * r2[1];
        const int ros[3] = {ro0, ro1, ro2};
#pragma unroll
        for (int r = 0; r < 3; ++r) {
            const float* row = pc + ros[r];
            const float2 m2 = *reinterpret_cast<const float2*>(row + xb);
            const float v[4] = {row[xm1], m2.x, m2.y, row[xp2]};
#pragma unroll
            for (int m = 0; m < 4; ++m) nrm2[r][m] += v[m] * v[m];
#pragma unroll
            for (int dx = 0; dx < 3; ++dx) {
                dot[r * 3 + dx][0] += r2[0] * v[dx];
                dot[r * 3 + dx][1] += r2[1] * v[1 + dx];
            }
        }
    }

    // ---- reduce partials across the 4 chunk-lanes (width-4 butterfly) ----
#pragma unroll
    for (int k = 0; k < 9; ++k)
#pragma unroll
        for (int jj = 0; jj < 2; ++jj) {
            float v = dot[k][jj];
            v += __shfl_xor(v, 1, 4);
            v += __shfl_xor(v, 2, 4);
            dot[k][jj] = v;
        }
#pragma unroll
    for (int r = 0; r < 3; ++r)
#pragma unroll
        for (int m = 0; m < 4; ++m) {
            float v = nrm2[r][m];
            v += __shfl_xor(v, 1, 4);
            v += __shfl_xor(v, 2, 4);
            nrm2[r][m] = v;
        }
#pragma unroll
    for (int jj = 0; jj < 2; ++jj) {
        float v = ref2[jj];
        v += __shfl_xor(v, 1, 4);
        v += __shfl_xor(v, 2, 4);
        ref2[jj] = v;
    }

    // ---- normalize, softmax over 9 neighbors per pixel (redundant in 4 lanes) ----
    float invn[3][4];
#pragma unroll
    for (int r = 0; r < 3; ++r)
#pragma unroll
        for (int m = 0; m < 4; ++m) invn[r][m] = rsqrtf(fmaxf(nrm2[r][m], 1e-24f));

    float wtp[9][2];     // softmax weight * inv-norm of that neighbor (folded)
#pragma unroll
    for (int jj = 0; jj < 2; ++jj) {
        const float invr = rsqrtf(fmaxf(ref2[jj], 1e-24f));
        float d[9];
#pragma unroll
        for (int r = 0; r < 3; ++r)
#pragma unroll
            for (int dx = 0; dx < 3; ++dx)
                d[r * 3 + dx] = dot[r * 3 + dx][jj] * invr * invn[r][jj + dx];
        float mx = d[0];
#pragma unroll
        for (int k = 1; k < 9; ++k) mx = fmaxf(mx, d[k]);
        float e[9], ssum = 0.f;
#pragma unroll
        for (int k = 0; k < 9; ++k) { e[k] = __expf(d[k] - mx); ssum += e[k]; }
        const float is = 1.f / ssum;
#pragma unroll
        for (int r = 0; r < 3; ++r)
#pragma unroll
            for (int dx = 0; dx < 3; ++dx)
                wtp[r * 3 + dx][jj] = e[r * 3 + dx] * is * invn[r][jj + dx];
    }

    // ---- pass 2 over this thread's channels: aggregate + wdiff + store ----
    const float* __restrict__ nbb = nbrs + (size_t)b * N_ * C_ * HW_;
    float* __restrict__ op = out + (size_t)(b * 5 + i) * C_ * HW_ + y * W_ + xb;
    for (int cc = 0; cc < 16; ++cc) {
        const int c = c0 + cc;
        const float* pc = nb + c * HW_;
        float agg[2] = {0.f, 0.f};
        float ctr[2] = {0.f, 0.f};
        const int ros[3] = {ro0, ro1, ro2};
#pragma unroll
        for (int r = 0; r < 3; ++r) {
            const float* row = pc + ros[r];
            const float2 m2 = *reinterpret_cast<const float2*>(row + xb);
            const float v[4] = {row[xm1], m2.x, m2.y, row[xp2]};
#pragma unroll
            for (int dx = 0; dx < 3; ++dx) {
                agg[0] += wtp[r * 3 + dx][0] * v[dx];
                agg[1] += wtp[r * 3 + dx][1] * v[1 + dx];
            }
            if (r == 1) { ctr[0] = v[1]; ctr[1] = v[2]; }
        }
        // mean over the 4 neighbor images; own image's center row is already in ctr
        float s0 = ctr[0], s1 = ctr[1];
#pragma unroll
        for (int ii = 0; ii < N_; ++ii) {
            if (ii == i) continue;   // block-uniform branch
            const float2 qv = *reinterpret_cast<const float2*>(nbb + (size_t)(ii * C_ + c) * HW_ + ro1 + xb);
            s0 += qv.x; s1 += qv.y;
        }
        const float d0 = ctr[0] - 0.25f * s0;
        const float d1 = ctr[1] - 0.25f * s1;
        float2 o2;
        o2.x = agg[0] * __expf(-d0 * d0);
        o2.y = agg[1] * __expf(-d1 * d1);
        *reinterpret_cast<float2*>(op + c * HW_) = o2;
    }
}

}  // namespace

extern "C" void kernel_launch(void* const* d_in, const int* in_sizes, int n_in,
                              void* d_out, int out_size, void* d_ws, size_t ws_size,
                              hipStream_t stream) {
    const float* nbrs = (const float*)d_in[0];
    const float* ref = (const float*)d_in[1];
    float* out = (float*)d_out;

    // slot 4 = ref copy: B*C*HW floats / 4 per thread / 256 per block
    copyref_kernel<<<(B_ * C_ * HW_ / 4) / 256, 256, 0, stream>>>(ref, out);

    // main: B*N*H = 2048 one-row blocks of 256 threads
    localcorr_kernel<<<B_ * N_ * H_, 256, 0, stream>>>(nbrs, ref, out);
}

// Round 8
// 158.442 us; speedup vs baseline: 2.7114x; 2.7114x over previous
//
#include <hip/hip_runtime.h>
#include <math.h>

namespace {

constexpr int B_ = 4, N_ = 4, C_ = 64, H_ = 128, W_ = 128;
constexpr int HW_ = H_ * W_;

// out[:, 4] = ref
__global__ __launch_bounds__(256) void copyref_kernel(const float* __restrict__ ref,
                                                      float* __restrict__ out) {
    int t = blockIdx.x * 256 + threadIdx.x;      // one float4 per thread
    int f = t * 4;
    int b = f / (C_ * HW_);
    int within = f - b * (C_ * HW_);
    float4 v = *reinterpret_cast<const float4*>(ref + (size_t)b * C_ * HW_ + within);
    *reinterpret_cast<float4*>(out + (size_t)(b * 5 + N_) * C_ * HW_ + within) = v;
}

__device__ __forceinline__ float4 ld4(const float* p) {
    return *reinterpret_cast<const float4*>(p);
}

// Main kernel: EXACT round-3 shape (lane-quad C-split, 4 px/thread, 2 rows/block,
// 1024 blocks) + depth-1 software prefetch in both channel loops.
//   thread -> (pixel-group of 4 x, channel-chunk q of 16 channels); q = tid & 3.
__global__ __launch_bounds__(256, 4) void localcorr_kernel(const float* __restrict__ nbrs,
                                                           const float* __restrict__ ref,
                                                           float* __restrict__ out) {
    const int blk = blockIdx.x;
    const int ypair = blk & 63;      // H/2 = 64
    const int bi = blk >> 6;
    const int i = bi & 3;
    const int b = bi >> 2;
    const int tid = (int)threadIdx.x;
    const int q = tid & 3;           // channel chunk
    const int g = tid >> 2;          // pixel group 0..63
    const int y = ypair * 2 + (g >> 5);
    const int xb = (g & 31) * 4;
    const int c0 = q * 16;

    // reflect-pad (np 'reflect', pad=1): idx -1 -> 1, idx W -> W-2
    const int ym1 = (y == 0) ? 1 : y - 1;
    const int yp1 = (y == H_ - 1) ? H_ - 2 : y + 1;
    const int xm1 = (xb == 0) ? 1 : xb - 1;
    const int xp4 = (xb + 4 == W_) ? W_ - 2 : xb + 4;

    const int ro0 = ym1 * W_, ro1 = y * W_, ro2 = yp1 * W_;

    // thread-channel bases
    const float* __restrict__ nbc = nbrs + (size_t)(b * N_ + i) * C_ * HW_ + (size_t)c0 * HW_;
    const float* __restrict__ rpc = ref + (size_t)b * C_ * HW_ + (size_t)c0 * HW_ + y * W_ + xb;

    float dot[9][4];     // partial dots over this thread's 16 channels
    float nrm2[3][6];    // partial sq-norms, 3 rows x 6 cols (xb-1 .. xb+4)
    float ref2[4];       // partial ref sq-norms
#pragma unroll
    for (int k = 0; k < 9; ++k)
#pragma unroll
        for (int jj = 0; jj < 4; ++jj) dot[k][jj] = 0.f;
#pragma unroll
    for (int r = 0; r < 3; ++r)
#pragma unroll
        for (int m = 0; m < 6; ++m) nrm2[r][m] = 0.f;
#pragma unroll
    for (int jj = 0; jj < 4; ++jj) ref2[jj] = 0.f;

    // ---- pass 1 over this thread's channels, depth-1 prefetch ----
    float4 rv_n = ld4(rpc);
    float4 a0_n = ld4(nbc + ro0 + xb);
    float4 a1_n = ld4(nbc + ro1 + xb);
    float4 a2_n = ld4(nbc + ro2 + xb);
#pragma unroll 2
    for (int cc = 0; cc < 16; ++cc) {
        const float4 rv = rv_n, a0 = a0_n, a1 = a1_n, a2 = a2_n;
        const int cn = (cc + 1) & 15;           // wrap: last prefetch harmless
        rv_n = ld4(rpc + cn * HW_);
        a0_n = ld4(nbc + cn * HW_ + ro0 + xb);
        a1_n = ld4(nbc + cn * HW_ + ro1 + xb);
        a2_n = ld4(nbc + cn * HW_ + ro2 + xb);
        // edge scalars (same cache lines as neighbor lanes' float4s)
        const float* pc = nbc + cc * HW_;
        const float v0[6] = {pc[ro0 + xm1], a0.x, a0.y, a0.z, a0.w, pc[ro0 + xp4]};
        const float v1[6] = {pc[ro1 + xm1], a1.x, a1.y, a1.z, a1.w, pc[ro1 + xp4]};
        const float v2[6] = {pc[ro2 + xm1], a2.x, a2.y, a2.z, a2.w, pc[ro2 + xp4]};
        const float r4[4] = {rv.x, rv.y, rv.z, rv.w};
#pragma unroll
        for (int jj = 0; jj < 4; ++jj) ref2[jj] += r4[jj] * r4[jj];
#pragma unroll
        for (int m = 0; m < 6; ++m) {
            nrm2[0][m] += v0[m] * v0[m];
            nrm2[1][m] += v1[m] * v1[m];
            nrm2[2][m] += v2[m] * v2[m];
        }
#pragma unroll
        for (int dx = 0; dx < 3; ++dx) {
#pragma unroll
            for (int jj = 0; jj < 4; ++jj) {
                dot[0 + dx][jj] += r4[jj] * v0[jj + dx];
                dot[3 + dx][jj] += r4[jj] * v1[jj + dx];
                dot[6 + dx][jj] += r4[jj] * v2[jj + dx];
            }
        }
    }

    // ---- reduce partials across the 4 chunk-lanes (width-4 butterfly) ----
#pragma unroll
    for (int k = 0; k < 9; ++k)
#pragma unroll
        for (int jj = 0; jj < 4; ++jj) {
            float v = dot[k][jj];
            v += __shfl_xor(v, 1, 4);
            v += __shfl_xor(v, 2, 4);
            dot[k][jj] = v;
        }
#pragma unroll
    for (int r = 0; r < 3; ++r)
#pragma unroll
        for (int m = 0; m < 6; ++m) {
            float v = nrm2[r][m];
            v += __shfl_xor(v, 1, 4);
            v += __shfl_xor(v, 2, 4);
            nrm2[r][m] = v;
        }
#pragma unroll
    for (int jj = 0; jj < 4; ++jj) {
        float v = ref2[jj];
        v += __shfl_xor(v, 1, 4);
        v += __shfl_xor(v, 2, 4);
        ref2[jj] = v;
    }

    // ---- normalize, softmax over 9 neighbors per pixel (redundant in 4 lanes) ----
    float invn[3][6];
#pragma unroll
    for (int r = 0; r < 3; ++r)
#pragma unroll
        for (int m = 0; m < 6; ++m) invn[r][m] = rsqrtf(fmaxf(nrm2[r][m], 1e-24f));

    float wtp[9][4];     // softmax weight * inv-norm of that neighbor (folded)
#pragma unroll
    for (int jj = 0; jj < 4; ++jj) {
        const float invr = rsqrtf(fmaxf(ref2[jj], 1e-24f));
        float d[9];
#pragma unroll
        for (int r = 0; r < 3; ++r)
#pragma unroll
            for (int dx = 0; dx < 3; ++dx)
                d[r * 3 + dx] = dot[r * 3 + dx][jj] * invr * invn[r][jj + dx];
        float mx = d[0];
#pragma unroll
        for (int k = 1; k < 9; ++k) mx = fmaxf(mx, d[k]);
        float e[9], ssum = 0.f;
#pragma unroll
        for (int k = 0; k < 9; ++k) { e[k] = __expf(d[k] - mx); ssum += e[k]; }
        const float is = 1.f / ssum;
#pragma unroll
        for (int r = 0; r < 3; ++r)
#pragma unroll
            for (int dx = 0; dx < 3; ++dx)
                wtp[r * 3 + dx][jj] = e[r * 3 + dx] * is * invn[r][jj + dx];
    }

    // ---- pass 2: aggregate + wdiff + store, depth-1 prefetch ----
    const float* __restrict__ nbb = nbrs + (size_t)b * N_ * C_ * HW_;
    // the 3 other images (block-uniform), at this thread's channel base
    const float* __restrict__ pm0 = nbb + (size_t)(((i + 1) & 3) * C_ + c0) * HW_ + ro1 + xb;
    const float* __restrict__ pm1 = nbb + (size_t)(((i + 2) & 3) * C_ + c0) * HW_ + ro1 + xb;
    const float* __restrict__ pm2 = nbb + (size_t)(((i + 3) & 3) * C_ + c0) * HW_ + ro1 + xb;
    float* __restrict__ op = out + (size_t)(b * 5 + i) * C_ * HW_ + (size_t)c0 * HW_ + y * W_ + xb;

    float4 b0_n = ld4(nbc + ro0 + xb);
    float4 b1_n = ld4(nbc + ro1 + xb);
    float4 b2_n = ld4(nbc + ro2 + xb);
    float4 q0_n = ld4(pm0);
    float4 q1_n = ld4(pm1);
    float4 q2_n = ld4(pm2);
#pragma unroll 2
    for (int cc = 0; cc < 16; ++cc) {
        const float4 b0 = b0_n, b1 = b1_n, b2 = b2_n;
        const float4 q0 = q0_n, q1 = q1_n, q2 = q2_n;
        const int cn = (cc + 1) & 15;
        b0_n = ld4(nbc + cn * HW_ + ro0 + xb);
        b1_n = ld4(nbc + cn * HW_ + ro1 + xb);
        b2_n = ld4(nbc + cn * HW_ + ro2 + xb);
        q0_n = ld4(pm0 + cn * HW_);
        q1_n = ld4(pm1 + cn * HW_);
        q2_n = ld4(pm2 + cn * HW_);

        const float* pc = nbc + cc * HW_;
        const float v0[6] = {pc[ro0 + xm1], b0.x, b0.y, b0.z, b0.w, pc[ro0 + xp4]};
        const float v1[6] = {pc[ro1 + xm1], b1.x, b1.y, b1.z, b1.w, pc[ro1 + xp4]};
        const float v2[6] = {pc[ro2 + xm1], b2.x, b2.y, b2.z, b2.w, pc[ro2 + xp4]};

        float agg[4] = {0.f, 0.f, 0.f, 0.f};
#pragma unroll
        for (int dx = 0; dx < 3; ++dx) {
#pragma unroll
            for (int jj = 0; jj < 4; ++jj) {
                agg[jj] += wtp[0 + dx][jj] * v0[jj + dx];
                agg[jj] += wtp[3 + dx][jj] * v1[jj + dx];
                agg[jj] += wtp[6 + dx][jj] * v2[jj + dx];
            }
        }
        const float ctr[4] = {v1[1], v1[2], v1[3], v1[4]};
        const float s4[4] = {ctr[0] + q0.x + q1.x + q2.x,
                             ctr[1] + q0.y + q1.y + q2.y,
                             ctr[2] + q0.z + q1.z + q2.z,
                             ctr[3] + q0.w + q1.w + q2.w};
        float o[4];
#pragma unroll
        for (int jj = 0; jj < 4; ++jj) {
            const float dd = ctr[jj] - 0.25f * s4[jj];
            o[jj] = agg[jj] * __expf(-dd * dd);
        }
        float4 o4; o4.x = o[0]; o4.y = o[1]; o4.z = o[2]; o4.w = o[3];
        *reinterpret_cast<float4*>(op + cc * HW_) = o4;
    }
}

}  // namespace

extern "C" void kernel_launch(void* const* d_in, const int* in_sizes, int n_in,
                              void* d_out, int out_size, void* d_ws, size_t ws_size,
                              hipStream_t stream) {
    const float* nbrs = (const float*)d_in[0];
    const float* ref = (const float*)d_in[1];
    float* out = (float*)d_out;

    // slot 4 = ref copy: B*C*HW floats / 4 per thread / 256 per block
    copyref_kernel<<<(B_ * C_ * HW_ / 4) / 256, 256, 0, stream>>>(ref, out);

    // main: B*N*(H/2) = 1024 blocks (round-3 proven grid)
    localcorr_kernel<<<B_ * N_ * (H_ / 2), 256, 0, stream>>>(nbrs, ref, out);
}

// Round 9
// 123.725 us; speedup vs baseline: 3.4723x; 1.2806x over previous
//
#include <hip/hip_runtime.h>
#include <math.h>

namespace {

constexpr int B_ = 4, N_ = 4, C_ = 64, H_ = 128, W_ = 128;
constexpr int HW_ = H_ * W_;

// out[:, 4] = ref
__global__ __launch_bounds__(256) void copyref_kernel(const float* __restrict__ ref,
                                                      float* __restrict__ out) {
    int t = blockIdx.x * 256 + threadIdx.x;      // one float4 per thread
    int f = t * 4;
    int b = f / (C_ * HW_);
    int within = f - b * (C_ * HW_);
    float4 v = *reinterpret_cast<const float4*>(ref + (size_t)b * C_ * HW_ + within);
    *reinterpret_cast<float4*>(out + (size_t)(b * 5 + N_) * C_ * HW_ + within) = v;
}

__device__ __forceinline__ float4 ld4(const float* p) {
    return *reinterpret_cast<const float4*>(p);
}

// Main kernel: round-3 shape (lane-quad C-split, 4 px/thread, 2 rows/block,
// 1024 blocks) + depth-1 software prefetch in both channel loops.
// NOTE: __launch_bounds__(256) WITHOUT a min-waves arg — rounds 4/6/7/8 showed
// the allocator clamps to the 64-VGPR occupancy granule and spills when a
// min-waves hint is present (VGPR reported 32/64/64/64 + scratch traffic);
// round 0 with plain (256) got VGPR=80 spill-free.
__global__ __launch_bounds__(256) void localcorr_kernel(const float* __restrict__ nbrs,
                                                        const float* __restrict__ ref,
                                                        float* __restrict__ out) {
    const int blk = blockIdx.x;
    const int ypair = blk & 63;      // H/2 = 64
    const int bi = blk >> 6;
    const int i = bi & 3;
    const int b = bi >> 2;
    const int tid = (int)threadIdx.x;
    const int q = tid & 3;           // channel chunk
    const int g = tid >> 2;          // pixel group 0..63
    const int y = ypair * 2 + (g >> 5);
    const int xb = (g & 31) * 4;
    const int c0 = q * 16;

    // reflect-pad (np 'reflect', pad=1): idx -1 -> 1, idx W -> W-2
    const int ym1 = (y == 0) ? 1 : y - 1;
    const int yp1 = (y == H_ - 1) ? H_ - 2 : y + 1;
    const int xm1 = (xb == 0) ? 1 : xb - 1;
    const int xp4 = (xb + 4 == W_) ? W_ - 2 : xb + 4;

    const int ro0 = ym1 * W_, ro1 = y * W_, ro2 = yp1 * W_;

    // thread-channel bases
    const float* __restrict__ nbc = nbrs + (size_t)(b * N_ + i) * C_ * HW_ + (size_t)c0 * HW_;
    const float* __restrict__ rpc = ref + (size_t)b * C_ * HW_ + (size_t)c0 * HW_ + y * W_ + xb;

    float dot[9][4];     // partial dots over this thread's 16 channels
    float nrm2[3][6];    // partial sq-norms, 3 rows x 6 cols (xb-1 .. xb+4)
    float ref2[4];       // partial ref sq-norms
#pragma unroll
    for (int k = 0; k < 9; ++k)
#pragma unroll
        for (int jj = 0; jj < 4; ++jj) dot[k][jj] = 0.f;
#pragma unroll
    for (int r = 0; r < 3; ++r)
#pragma unroll
        for (int m = 0; m < 6; ++m) nrm2[r][m] = 0.f;
#pragma unroll
    for (int jj = 0; jj < 4; ++jj) ref2[jj] = 0.f;

    // ---- pass 1 over this thread's channels, depth-1 prefetch ----
    float4 rv_n = ld4(rpc);
    float4 a0_n = ld4(nbc + ro0 + xb);
    float4 a1_n = ld4(nbc + ro1 + xb);
    float4 a2_n = ld4(nbc + ro2 + xb);
#pragma unroll 2
    for (int cc = 0; cc < 16; ++cc) {
        const float4 rv = rv_n, a0 = a0_n, a1 = a1_n, a2 = a2_n;
        const int cn = (cc + 1) & 15;           // wrap: last prefetch harmless
        rv_n = ld4(rpc + cn * HW_);
        a0_n = ld4(nbc + cn * HW_ + ro0 + xb);
        a1_n = ld4(nbc + cn * HW_ + ro1 + xb);
        a2_n = ld4(nbc + cn * HW_ + ro2 + xb);
        // edge scalars (same cache lines as neighbor lanes' float4s)
        const float* pc = nbc + cc * HW_;
        const float v0[6] = {pc[ro0 + xm1], a0.x, a0.y, a0.z, a0.w, pc[ro0 + xp4]};
        const float v1[6] = {pc[ro1 + xm1], a1.x, a1.y, a1.z, a1.w, pc[ro1 + xp4]};
        const float v2[6] = {pc[ro2 + xm1], a2.x, a2.y, a2.z, a2.w, pc[ro2 + xp4]};
        const float r4[4] = {rv.x, rv.y, rv.z, rv.w};
#pragma unroll
        for (int jj = 0; jj < 4; ++jj) ref2[jj] += r4[jj] * r4[jj];
#pragma unroll
        for (int m = 0; m < 6; ++m) {
            nrm2[0][m] += v0[m] * v0[m];
            nrm2[1][m] += v1[m] * v1[m];
            nrm2[2][m] += v2[m] * v2[m];
        }
#pragma unroll
        for (int dx = 0; dx < 3; ++dx) {
#pragma unroll
            for (int jj = 0; jj < 4; ++jj) {
                dot[0 + dx][jj] += r4[jj] * v0[jj + dx];
                dot[3 + dx][jj] += r4[jj] * v1[jj + dx];
                dot[6 + dx][jj] += r4[jj] * v2[jj + dx];
            }
        }
    }

    // ---- reduce partials across the 4 chunk-lanes (width-4 butterfly) ----
#pragma unroll
    for (int k = 0; k < 9; ++k)
#pragma unroll
        for (int jj = 0; jj < 4; ++jj) {
            float v = dot[k][jj];
            v += __shfl_xor(v, 1, 4);
            v += __shfl_xor(v, 2, 4);
            dot[k][jj] = v;
        }
#pragma unroll
    for (int r = 0; r < 3; ++r)
#pragma unroll
        for (int m = 0; m < 6; ++m) {
            float v = nrm2[r][m];
            v += __shfl_xor(v, 1, 4);
            v += __shfl_xor(v, 2, 4);
            nrm2[r][m] = v;
        }
#pragma unroll
    for (int jj = 0; jj < 4; ++jj) {
        float v = ref2[jj];
        v += __shfl_xor(v, 1, 4);
        v += __shfl_xor(v, 2, 4);
        ref2[jj] = v;
    }

    // ---- normalize, softmax over 9 neighbors per pixel (redundant in 4 lanes) ----
    float invn[3][6];
#pragma unroll
    for (int r = 0; r < 3; ++r)
#pragma unroll
        for (int m = 0; m < 6; ++m) invn[r][m] = rsqrtf(fmaxf(nrm2[r][m], 1e-24f));

    float wtp[9][4];     // softmax weight * inv-norm of that neighbor (folded)
#pragma unroll
    for (int jj = 0; jj < 4; ++jj) {
        const float invr = rsqrtf(fmaxf(ref2[jj], 1e-24f));
        float d[9];
#pragma unroll
        for (int r = 0; r < 3; ++r)
#pragma unroll
            for (int dx = 0; dx < 3; ++dx)
                d[r * 3 + dx] = dot[r * 3 + dx][jj] * invr * invn[r][jj + dx];
        float mx = d[0];
#pragma unroll
        for (int k = 1; k < 9; ++k) mx = fmaxf(mx, d[k]);
        float e[9], ssum = 0.f;
#pragma unroll
        for (int k = 0; k < 9; ++k) { e[k] = __expf(d[k] - mx); ssum += e[k]; }
        const float is = 1.f / ssum;
#pragma unroll
        for (int r = 0; r < 3; ++r)
#pragma unroll
            for (int dx = 0; dx < 3; ++dx)
                wtp[r * 3 + dx][jj] = e[r * 3 + dx] * is * invn[r][jj + dx];
    }

    // ---- pass 2: aggregate + wdiff + store, depth-1 prefetch ----
    const float* __restrict__ nbb = nbrs + (size_t)b * N_ * C_ * HW_;
    // the 3 other images (block-uniform), at this thread's channel base
    const float* __restrict__ pm0 = nbb + (size_t)(((i + 1) & 3) * C_ + c0) * HW_ + ro1 + xb;
    const float* __restrict__ pm1 = nbb + (size_t)(((i + 2) & 3) * C_ + c0) * HW_ + ro1 + xb;
    const float* __restrict__ pm2 = nbb + (size_t)(((i + 3) & 3) * C_ + c0) * HW_ + ro1 + xb;
    float* __restrict__ op = out + (size_t)(b * 5 + i) * C_ * HW_ + (size_t)c0 * HW_ + y * W_ + xb;

    float4 b0_n = ld4(nbc + ro0 + xb);
    float4 b1_n = ld4(nbc + ro1 + xb);
    float4 b2_n = ld4(nbc + ro2 + xb);
    float4 q0_n = ld4(pm0);
    float4 q1_n = ld4(pm1);
    float4 q2_n = ld4(pm2);
#pragma unroll 2
    for (int cc = 0; cc < 16; ++cc) {
        const float4 b0 = b0_n, b1 = b1_n, b2 = b2_n;
        const float4 q0 = q0_n, q1 = q1_n, q2 = q2_n;
        const int cn = (cc + 1) & 15;
        b0_n = ld4(nbc + cn * HW_ + ro0 + xb);
        b1_n = ld4(nbc + cn * HW_ + ro1 + xb);
        b2_n = ld4(nbc + cn * HW_ + ro2 + xb);
        q0_n = ld4(pm0 + cn * HW_);
        q1_n = ld4(pm1 + cn * HW_);
        q2_n = ld4(pm2 + cn * HW_);

        const float* pc = nbc + cc * HW_;
        const float v0[6] = {pc[ro0 + xm1], b0.x, b0.y, b0.z, b0.w, pc[ro0 + xp4]};
        const float v1[6] = {pc[ro1 + xm1], b1.x, b1.y, b1.z, b1.w, pc[ro1 + xp4]};
        const float v2[6] = {pc[ro2 + xm1], b2.x, b2.y, b2.z, b2.w, pc[ro2 + xp4]};

        float agg[4] = {0.f, 0.f, 0.f, 0.f};
#pragma unroll
        for (int dx = 0; dx < 3; ++dx) {
#pragma unroll
            for (int jj = 0; jj < 4; ++jj) {
                agg[jj] += wtp[0 + dx][jj] * v0[jj + dx];
                agg[jj] += wtp[3 + dx][jj] * v1[jj + dx];
                agg[jj] += wtp[6 + dx][jj] * v2[jj + dx];
            }
        }
        const float ctr[4] = {v1[1], v1[2], v1[3], v1[4]};
        const float s4[4] = {ctr[0] + q0.x + q1.x + q2.x,
                             ctr[1] + q0.y + q1.y + q2.y,
                             ctr[2] + q0.z + q1.z + q2.z,
                             ctr[3] + q0.w + q1.w + q2.w};
        float o[4];
#pragma unroll
        for (int jj = 0; jj < 4; ++jj) {
            const float dd = ctr[jj] - 0.25f * s4[jj];
            o[jj] = agg[jj] * __expf(-dd * dd);
        }
        float4 o4; o4.x = o[0]; o4.y = o[1]; o4.z = o[2]; o4.w = o[3];
        *reinterpret_cast<float4*>(op + cc * HW_) = o4;
    }
}

}  // namespace

extern "C" void kernel_launch(void* const* d_in, const int* in_sizes, int n_in,
                              void* d_out, int out_size, void* d_ws, size_t ws_size,
                              hipStream_t stream) {
    const float* nbrs = (const float*)d_in[0];
    const float* ref = (const float*)d_in[1];
    float* out = (float*)d_out;

    // slot 4 = ref copy: B*C*HW floats / 4 per thread / 256 per block
    copyref_kernel<<<(B_ * C_ * HW_ / 4) / 256, 256, 0, stream>>>(ref, out);

    // main: B*N*(H/2) = 1024 blocks (round-3 proven grid)
    localcorr_kernel<<<B_ * N_ * (H_ / 2), 256, 0, stream>>>(nbrs, ref, out);
}

// Round 11
// 117.614 us; speedup vs baseline: 3.6527x; 1.0520x over previous
//
#include <hip/hip_runtime.h>
#include <math.h>

namespace {

constexpr int B_ = 4, N_ = 4, C_ = 64, H_ = 128, W_ = 128;
constexpr int HW_ = H_ * W_;

// out[:, 4] = ref
__global__ __launch_bounds__(256) void copyref_kernel(const float* __restrict__ ref,
                                                      float* __restrict__ out) {
    int t = blockIdx.x * 256 + threadIdx.x;      // one float4 per thread
    int f = t * 4;
    int b = f / (C_ * HW_);
    int within = f - b * (C_ * HW_);
    float4 v = *reinterpret_cast<const float4*>(ref + (size_t)b * C_ * HW_ + within);
    *reinterpret_cast<float4*>(out + (size_t)(b * 5 + N_) * C_ * HW_ + within) = v;
}

__device__ __forceinline__ float4 ld4(const float* p) {
    return *reinterpret_cast<const float4*>(p);
}

// Main kernel: round-9 body (lane-quad C-split, 4 px/thread, 2 rows/block,
// 1024 blocks, depth-1 prefetch) + (a) XCD-contiguous swizzle so XCD x owns
// images {2x,2x+1} with y-sequential ordering (stencil re-reads become L2 hits
// instead of L3), (b) edge scalars included in the prefetch batch (single
// wait point per iteration).
// Plain __launch_bounds__(256): min-waves hints provably caused spill (r4/6/7/8).
__global__ __launch_bounds__(256) void localcorr_kernel(const float* __restrict__ nbrs,
                                                        const float* __restrict__ ref,
                                                        float* __restrict__ out) {
    // swizzle: s = xcd + 8*k, k = (bi_within_xcd)*64 + ypair, bi = 2*xcd + (k>>6)
    const int s = blockIdx.x;        // 0..1023
    const int xcd = s & 7;
    const int k = s >> 3;            // 0..127
    const int bi = xcd * 2 + (k >> 6);
    const int ypair = k & 63;
    const int i = bi & 3;
    const int b = bi >> 2;
    const int tid = (int)threadIdx.x;
    const int q = tid & 3;           // channel chunk
    const int g = tid >> 2;          // pixel group 0..63
    const int y = ypair * 2 + (g >> 5);
    const int xb = (g & 31) * 4;
    const int c0 = q * 16;

    // reflect-pad (np 'reflect', pad=1): idx -1 -> 1, idx W -> W-2
    const int ym1 = (y == 0) ? 1 : y - 1;
    const int yp1 = (y == H_ - 1) ? H_ - 2 : y + 1;
    const int xm1 = (xb == 0) ? 1 : xb - 1;
    const int xp4 = (xb + 4 == W_) ? W_ - 2 : xb + 4;

    const int ro0 = ym1 * W_, ro1 = y * W_, ro2 = yp1 * W_;

    // thread-channel bases
    const float* __restrict__ nbc = nbrs + (size_t)(b * N_ + i) * C_ * HW_ + (size_t)c0 * HW_;
    const float* __restrict__ rpc = ref + (size_t)b * C_ * HW_ + (size_t)c0 * HW_ + y * W_ + xb;

    float dot[9][4];     // partial dots over this thread's 16 channels
    float nrm2[3][6];    // partial sq-norms, 3 rows x 6 cols (xb-1 .. xb+4)
    float ref2[4];       // partial ref sq-norms
#pragma unroll
    for (int kk = 0; kk < 9; ++kk)
#pragma unroll
        for (int jj = 0; jj < 4; ++jj) dot[kk][jj] = 0.f;
#pragma unroll
    for (int r = 0; r < 3; ++r)
#pragma unroll
        for (int m = 0; m < 6; ++m) nrm2[r][m] = 0.f;
#pragma unroll
    for (int jj = 0; jj < 4; ++jj) ref2[jj] = 0.f;

    // ---- pass 1 over this thread's channels, depth-1 prefetch (ALL loads) ----
    float4 rv_n = ld4(rpc);
    float4 a0_n = ld4(nbc + ro0 + xb);
    float4 a1_n = ld4(nbc + ro1 + xb);
    float4 a2_n = ld4(nbc + ro2 + xb);
    float e0m_n = nbc[ro0 + xm1], e0p_n = nbc[ro0 + xp4];
    float e1m_n = nbc[ro1 + xm1], e1p_n = nbc[ro1 + xp4];
    float e2m_n = nbc[ro2 + xm1], e2p_n = nbc[ro2 + xp4];
#pragma unroll 2
    for (int cc = 0; cc < 16; ++cc) {
        const float4 rv = rv_n, a0 = a0_n, a1 = a1_n, a2 = a2_n;
        const float e0m = e0m_n, e0p = e0p_n, e1m = e1m_n, e1p = e1p_n, e2m = e2m_n, e2p = e2p_n;
        const int cn = (cc + 1) & 15;           // wrap: last prefetch harmless
        const float* pn = nbc + cn * HW_;
        rv_n = ld4(rpc + cn * HW_);
        a0_n = ld4(pn + ro0 + xb);
        a1_n = ld4(pn + ro1 + xb);
        a2_n = ld4(pn + ro2 + xb);
        e0m_n = pn[ro0 + xm1]; e0p_n = pn[ro0 + xp4];
        e1m_n = pn[ro1 + xm1]; e1p_n = pn[ro1 + xp4];
        e2m_n = pn[ro2 + xm1]; e2p_n = pn[ro2 + xp4];

        const float v0[6] = {e0m, a0.x, a0.y, a0.z, a0.w, e0p};
        const float v1[6] = {e1m, a1.x, a1.y, a1.z, a1.w, e1p};
        const float v2[6] = {e2m, a2.x, a2.y, a2.z, a2.w, e2p};
        const float r4[4] = {rv.x, rv.y, rv.z, rv.w};
#pragma unroll
        for (int jj = 0; jj < 4; ++jj) ref2[jj] += r4[jj] * r4[jj];
#pragma unroll
        for (int m = 0; m < 6; ++m) {
            nrm2[0][m] += v0[m] * v0[m];
            nrm2[1][m] += v1[m] * v1[m];
            nrm2[2][m] += v2[m] * v2[m];
        }
#pragma unroll
        for (int dx = 0; dx < 3; ++dx) {
#pragma unroll
            for (int jj = 0; jj < 4; ++jj) {
                dot[0 + dx][jj] += r4[jj] * v0[jj + dx];
                dot[3 + dx][jj] += r4[jj] * v1[jj + dx];
                dot[6 + dx][jj] += r4[jj] * v2[jj + dx];
            }
        }
    }

    // ---- reduce partials across the 4 chunk-lanes (width-4 butterfly) ----
#pragma unroll
    for (int kk = 0; kk < 9; ++kk)
#pragma unroll
        for (int jj = 0; jj < 4; ++jj) {
            float v = dot[kk][jj];
            v += __shfl_xor(v, 1, 4);
            v += __shfl_xor(v, 2, 4);
            dot[kk][jj] = v;
        }
#pragma unroll
    for (int r = 0; r < 3; ++r)
#pragma unroll
        for (int m = 0; m < 6; ++m) {
            float v = nrm2[r][m];
            v += __shfl_xor(v, 1, 4);
            v += __shfl_xor(v, 2, 4);
            nrm2[r][m] = v;
        }
#pragma unroll
    for (int jj = 0; jj < 4; ++jj) {
        float v = ref2[jj];
        v += __shfl_xor(v, 1, 4);
        v += __shfl_xor(v, 2, 4);
        ref2[jj] = v;
    }

    // ---- normalize, softmax over 9 neighbors per pixel (redundant in 4 lanes) ----
    float invn[3][6];
#pragma unroll
    for (int r = 0; r < 3; ++r)
#pragma unroll
        for (int m = 0; m < 6; ++m) invn[r][m] = rsqrtf(fmaxf(nrm2[r][m], 1e-24f));

    float wtp[9][4];     // softmax weight * inv-norm of that neighbor (folded)
#pragma unroll
    for (int jj = 0; jj < 4; ++jj) {
        const float invr = rsqrtf(fmaxf(ref2[jj], 1e-24f));
        float d[9];
#pragma unroll
        for (int r = 0; r < 3; ++r)
#pragma unroll
            for (int dx = 0; dx < 3; ++dx)
                d[r * 3 + dx] = dot[r * 3 + dx][jj] * invr * invn[r][jj + dx];
        float mx = d[0];
#pragma unroll
        for (int kk = 1; kk < 9; ++kk) mx = fmaxf(mx, d[kk]);
        float e[9], ssum = 0.f;
#pragma unroll
        for (int kk = 0; kk < 9; ++kk) { e[kk] = __expf(d[kk] - mx); ssum += e[kk]; }
        const float is = 1.f / ssum;
#pragma unroll
        for (int r = 0; r < 3; ++r)
#pragma unroll
            for (int dx = 0; dx < 3; ++dx)
                wtp[r * 3 + dx][jj] = e[r * 3 + dx] * is * invn[r][jj + dx];
    }

    // ---- pass 2: aggregate + wdiff + store, depth-1 prefetch (ALL loads) ----
    const float* __restrict__ nbb = nbrs + (size_t)b * N_ * C_ * HW_;
    // the 3 other images (block-uniform), at this thread's channel base
    const float* __restrict__ pm0 = nbb + (size_t)(((i + 1) & 3) * C_ + c0) * HW_ + ro1 + xb;
    const float* __restrict__ pm1 = nbb + (size_t)(((i + 2) & 3) * C_ + c0) * HW_ + ro1 + xb;
    const float* __restrict__ pm2 = nbb + (size_t)(((i + 3) & 3) * C_ + c0) * HW_ + ro1 + xb;
    float* __restrict__ op = out + (size_t)(b * 5 + i) * C_ * HW_ + (size_t)c0 * HW_ + y * W_ + xb;

    float4 b0_n = ld4(nbc + ro0 + xb);
    float4 b1_n = ld4(nbc + ro1 + xb);
    float4 b2_n = ld4(nbc + ro2 + xb);
    float4 q0_n = ld4(pm0);
    float4 q1_n = ld4(pm1);
    float4 q2_n = ld4(pm2);
    float f0m_n = nbc[ro0 + xm1], f0p_n = nbc[ro0 + xp4];
    float f1m_n = nbc[ro1 + xm1], f1p_n = nbc[ro1 + xp4];
    float f2m_n = nbc[ro2 + xm1], f2p_n = nbc[ro2 + xp4];
#pragma unroll 2
    for (int cc = 0; cc < 16; ++cc) {
        const float4 b0 = b0_n, b1 = b1_n, b2 = b2_n;
        const float4 q0 = q0_n, q1 = q1_n, q2 = q2_n;
        const float f0m = f0m_n, f0p = f0p_n, f1m = f1m_n, f1p = f1p_n, f2m = f2m_n, f2p = f2p_n;
        const int cn = (cc + 1) & 15;
        const float* pn = nbc + cn * HW_;
        b0_n = ld4(pn + ro0 + xb);
        b1_n = ld4(pn + ro1 + xb);
        b2_n = ld4(pn + ro2 + xb);
        q0_n = ld4(pm0 + cn * HW_);
        q1_n = ld4(pm1 + cn * HW_);
        q2_n = ld4(pm2 + cn * HW_);
        f0m_n = pn[ro0 + xm1]; f0p_n = pn[ro0 + xp4];
        f1m_n = pn[ro1 + xm1]; f1p_n = pn[ro1 + xp4];
        f2m_n = pn[ro2 + xm1]; f2p_n = pn[ro2 + xp4];

        const float v0[6] = {f0m, b0.x, b0.y, b0.z, b0.w, f0p};
        const float v1[6] = {f1m, b1.x, b1.y, b1.z, b1.w, f1p};
        const float v2[6] = {f2m, b2.x, b2.y, b2.z, b2.w, f2p};

        float agg[4] = {0.f, 0.f, 0.f, 0.f};
#pragma unroll
        for (int dx = 0; dx < 3; ++dx) {
#pragma unroll
            for (int jj = 0; jj < 4; ++jj) {
                agg[jj] += wtp[0 + dx][jj] * v0[jj + dx];
                agg[jj] += wtp[3 + dx][jj] * v1[jj + dx];
                agg[jj] += wtp[6 + dx][jj] * v2[jj + dx];
            }
        }
        const float ctr[4] = {v1[1], v1[2], v1[3], v1[4]};
        const float s4[4] = {ctr[0] + q0.x + q1.x + q2.x,
                             ctr[1] + q0.y + q1.y + q2.y,
                             ctr[2] + q0.z + q1.z + q2.z,
                             ctr[3] + q0.w + q1.w + q2.w};
        float o[4];
#pragma unroll
        for (int jj = 0; jj < 4; ++jj) {
            const float dd = ctr[jj] - 0.25f * s4[jj];
            o[jj] = agg[jj] * __expf(-dd * dd);
        }
        float4 o4; o4.x = o[0]; o4.y = o[1]; o4.z = o[2]; o4.w = o[3];
        *reinterpret_cast<float4*>(op + cc * HW_) = o4;
    }
}

}  // namespace

extern "C" void kernel_launch(void* const* d_in, const int* in_sizes, int n_in,
                              void* d_out, int out_size, void* d_ws, size_t ws_size,
                              hipStream_t stream) {
    const float* nbrs = (const float*)d_in[0];
    const float* ref = (const float*)d_in[1];
    float* out = (float*)d_out;

    // slot 4 = ref copy: B*C*HW floats / 4 per thread / 256 per block
    copyref_kernel<<<(B_ * C_ * HW_ / 4) / 256, 256, 0, stream>>>(ref, out);

    // main: B*N*(H/2) = 1024 blocks (round-3 proven grid, XCD-contiguous swizzle)
    localcorr_kernel<<<B_ * N_ * (H_ / 2), 256, 0, stream>>>(nbrs, ref, out);
}

// Round 12
// 81.351 us; speedup vs baseline: 5.2809x; 1.4458x over previous
//
#include <hip/hip_runtime.h>
#include <math.h>

namespace {

constexpr int B_ = 4, N_ = 4, C_ = 64, H_ = 128, W_ = 128;
constexpr int HW_ = H_ * W_;

// out[:, 4] = ref
__global__ __launch_bounds__(256) void copyref_kernel(const float* __restrict__ ref,
                                                      float* __restrict__ out) {
    int t = blockIdx.x * 256 + threadIdx.x;      // one float4 per thread
    int f = t * 4;
    int b = f / (C_ * HW_);
    int within = f - b * (C_ * HW_);
    float4 v = *reinterpret_cast<const float4*>(ref + (size_t)b * C_ * HW_ + within);
    *reinterpret_cast<float4*>(out + (size_t)(b * 5 + N_) * C_ * HW_ + within) = v;
}

// One thread per pixel; block = 2 rows (256 threads); full channel loop per
// thread. Window norms = neighbor pixels' center norms, shared via LDS.
// Per channel: stage 4 own rows (y0-1..y0+2, reflected) into LDS double-buffer;
// dots/norms/ref2 accumulate in registers; 1 barrier per channel.
__global__ __launch_bounds__(256) void localcorr_kernel(const float* __restrict__ nbrs,
                                                        const float* __restrict__ ref,
                                                        float* __restrict__ out) {
    __shared__ float s_own[2][4][128];   // [buf][staged row][x]
    __shared__ float s_nrm[4][128];      // per-pixel sq-norms in staged-row space

    const int blk = blockIdx.x;          // 0..1023
    const int ypair = blk & 63;
    const int bi = blk >> 6;
    const int i = bi & 3;
    const int b = bi >> 2;
    const int t = (int)threadIdx.x;
    const int x = t & 127;
    const int ry = t >> 7;               // 0/1, wave-uniform
    const int y0 = ypair * 2;
    const int y = y0 + ry;

    // reflect-pad (np 'reflect', pad=1)
    const int xm = (x == 0) ? 1 : x - 1;
    const int xp = (x == W_ - 1) ? W_ - 2 : x + 1;
    // staged rows 0..3 = actual rows y0-1, y0, y0+1, y0+2 (reflected)
    const int gyA = (y0 == 0) ? 1 : y0 - 1;
    const int gyB = y0;
    const int gyC = y0 + 1;
    const int gyD = (y0 + 2 == H_) ? H_ - 2 : y0 + 2;
    // this thread stages staged-rows {2ry, 2ry+1}
    const int myRowA = (ry == 0) ? gyA : gyC;
    const int myRowB = (ry == 0) ? gyB : gyD;

    const float* __restrict__ nb = nbrs + (size_t)(b * N_ + i) * C_ * HW_;
    const float* __restrict__ rp = ref + (size_t)b * C_ * HW_;
    const int offA = myRowA * W_ + x;
    const int offB = myRowB * W_ + x;
    const int offR = y * W_ + x;

    float dot[9];
#pragma unroll
    for (int k = 0; k < 9; ++k) dot[k] = 0.f;
    float nA = 0.f, nB = 0.f, r2 = 0.f;

    // ---- pass 1: dots + norms + ref2, LDS-staged, depth-1 reg pipeline ----
    float o0 = nb[offA], o1 = nb[offB], rf = rp[offR];
#pragma unroll 1
    for (int c = 0; c < C_; ++c) {
        const int cur = c & 1;
        s_own[cur][2 * ry + 0][x] = o0;
        s_own[cur][2 * ry + 1][x] = o1;
        float o0n = 0.f, o1n = 0.f, rfn = 0.f;
        if (c + 1 < C_) {
            const size_t co = (size_t)(c + 1) * HW_;
            o0n = nb[co + offA];
            o1n = nb[co + offB];
            rfn = rp[co + offR];
        }
        __syncthreads();
        // 3x3 window of this pixel: staged rows ry..ry+2, cols xm,x,xp
        const float w00 = s_own[cur][ry + 0][xm], w02 = s_own[cur][ry + 0][xp];
        const float w10 = s_own[cur][ry + 1][xm], w12 = s_own[cur][ry + 1][xp];
        const float w20 = s_own[cur][ry + 2][xm], w22 = s_own[cur][ry + 2][xp];
        float w01, w11, w21;
        if (ry == 0) { w01 = o0; w11 = o1; w21 = s_own[cur][2][x]; }
        else         { w01 = s_own[cur][1][x]; w11 = o0; w21 = o1; }
        nA += o0 * o0; nB += o1 * o1; r2 += rf * rf;
        dot[0] += rf * w00; dot[1] += rf * w01; dot[2] += rf * w02;
        dot[3] += rf * w10; dot[4] += rf * w11; dot[5] += rf * w12;
        dot[6] += rf * w20; dot[7] += rf * w21; dot[8] += rf * w22;
        o0 = o0n; o1 = o1n; rf = rfn;
    }

    // ---- share norms, softmax in-register ----
    s_nrm[2 * ry + 0][x] = nA;
    s_nrm[2 * ry + 1][x] = nB;
    __syncthreads();
    float nk[9];
    nk[0] = s_nrm[ry + 0][xm]; nk[1] = s_nrm[ry + 0][x]; nk[2] = s_nrm[ry + 0][xp];
    nk[3] = s_nrm[ry + 1][xm]; nk[4] = s_nrm[ry + 1][x]; nk[5] = s_nrm[ry + 1][xp];
    nk[6] = s_nrm[ry + 2][xm]; nk[7] = s_nrm[ry + 2][x]; nk[8] = s_nrm[ry + 2][xp];

    const float invr = rsqrtf(fmaxf(r2, 1e-24f));
    float inv[9], d[9];
#pragma unroll
    for (int k = 0; k < 9; ++k) {
        inv[k] = rsqrtf(fmaxf(nk[k], 1e-24f));
        d[k] = dot[k] * invr * inv[k];
    }
    float mx = d[0];
#pragma unroll
    for (int k = 1; k < 9; ++k) mx = fmaxf(mx, d[k]);
    float ssum = 0.f;
#pragma unroll
    for (int k = 0; k < 9; ++k) { d[k] = __expf(d[k] - mx); ssum += d[k]; }
    const float is = 1.f / ssum;
    float wtp[9];
#pragma unroll
    for (int k = 0; k < 9; ++k) wtp[k] = d[k] * is * inv[k];

    // ---- pass 2: aggregate + wdiff + store ----
    const float* __restrict__ pm0 = nbrs + (size_t)(b * N_ + ((i + 1) & 3)) * C_ * HW_;
    const float* __restrict__ pm1 = nbrs + (size_t)(b * N_ + ((i + 2) & 3)) * C_ * HW_;
    const float* __restrict__ pm2 = nbrs + (size_t)(b * N_ + ((i + 3) & 3)) * C_ * HW_;
    float* __restrict__ op = out + (size_t)(b * 5 + i) * C_ * HW_ + offR;

    o0 = nb[offA]; o1 = nb[offB];
    float q0 = pm0[offR], q1 = pm1[offR], q2 = pm2[offR];
#pragma unroll 1
    for (int c = 0; c < C_; ++c) {
        const int cur = c & 1;
        s_own[cur][2 * ry + 0][x] = o0;
        s_own[cur][2 * ry + 1][x] = o1;
        float o0n = 0.f, o1n = 0.f, q0n = 0.f, q1n = 0.f, q2n = 0.f;
        if (c + 1 < C_) {
            const size_t co = (size_t)(c + 1) * HW_;
            o0n = nb[co + offA];
            o1n = nb[co + offB];
            q0n = pm0[co + offR];
            q1n = pm1[co + offR];
            q2n = pm2[co + offR];
        }
        __syncthreads();
        const float w00 = s_own[cur][ry + 0][xm], w02 = s_own[cur][ry + 0][xp];
        const float w10 = s_own[cur][ry + 1][xm], w12 = s_own[cur][ry + 1][xp];
        const float w20 = s_own[cur][ry + 2][xm], w22 = s_own[cur][ry + 2][xp];
        float w01, w11, w21;
        if (ry == 0) { w01 = o0; w11 = o1; w21 = s_own[cur][2][x]; }
        else         { w01 = s_own[cur][1][x]; w11 = o0; w21 = o1; }
        const float agg = wtp[0] * w00 + wtp[1] * w01 + wtp[2] * w02
                        + wtp[3] * w10 + wtp[4] * w11 + wtp[5] * w12
                        + wtp[6] * w20 + wtp[7] * w21 + wtp[8] * w22;
        const float ctr = w11;
        const float dd = ctr - 0.25f * (ctr + q0 + q1 + q2);
        op[(size_t)c * HW_] = agg * __expf(-dd * dd);
        o0 = o0n; o1 = o1n; q0 = q0n; q1 = q1n; q2 = q2n;
    }
}

}  // namespace

extern "C" void kernel_launch(void* const* d_in, const int* in_sizes, int n_in,
                              void* d_out, int out_size, void* d_ws, size_t ws_size,
                              hipStream_t stream) {
    const float* nbrs = (const float*)d_in[0];
    const float* ref = (const float*)d_in[1];
    float* out = (float*)d_out;

    // slot 4 = ref copy
    copyref_kernel<<<(B_ * C_ * HW_ / 4) / 256, 256, 0, stream>>>(ref, out);

    // main: B*N*(H/2) = 1024 two-row blocks of 256 threads
    localcorr_kernel<<<B_ * N_ * (H_ / 2), 256, 0, stream>>>(nbrs, ref, out);
}

// Round 14
// 74.434 us; speedup vs baseline: 5.7717x; 1.0929x over previous
//
#include <hip/hip_runtime.h>
#include <math.h>

namespace {

constexpr int B_ = 4, N_ = 4, C_ = 64, H_ = 128, W_ = 128;
constexpr int HW_ = H_ * W_;
constexpr int CPB = 4;               // channels per barrier window
constexpr int NWIN = C_ / CPB;       // 16 windows

// out[:, 4] = ref
__global__ __launch_bounds__(256) void copyref_kernel(const float* __restrict__ ref,
                                                      float* __restrict__ out) {
    int t = blockIdx.x * 256 + threadIdx.x;      // one float4 per thread
    int f = t * 4;
    int b = f / (C_ * HW_);
    int within = f - b * (C_ * HW_);
    float4 v = *reinterpret_cast<const float4*>(ref + (size_t)b * C_ * HW_ + within);
    *reinterpret_cast<float4*>(out + (size_t)(b * 5 + N_) * C_ * HW_ + within) = v;
}

// One thread per pixel; block = 2 rows (256 threads); full channel loop.
// Window norms = neighbor pixels' center norms, shared via LDS.
// CPB=4 channels staged per barrier (double-buffered 8 slots), next window's
// global loads issued before the sync -> latency hidden under 4 channels of VALU.
__global__ __launch_bounds__(256) void localcorr_kernel(const float* __restrict__ nbrs,
                                                        const float* __restrict__ ref,
                                                        float* __restrict__ out) {
    __shared__ float s_own[2 * CPB][4][128];   // [slot][staged row][x]
    __shared__ float s_nrm[4][128];            // per-pixel sq-norms

    const int blk = blockIdx.x;          // 0..1023
    const int ypair = blk & 63;
    const int bi = blk >> 6;
    const int i = bi & 3;
    const int b = bi >> 2;
    const int t = (int)threadIdx.x;
    const int x = t & 127;
    const int ry = t >> 7;               // 0/1, wave-uniform
    const int y0 = ypair * 2;
    const int y = y0 + ry;

    // reflect-pad (np 'reflect', pad=1)
    const int xm = (x == 0) ? 1 : x - 1;
    const int xp = (x == W_ - 1) ? W_ - 2 : x + 1;
    const int gyA = (y0 == 0) ? 1 : y0 - 1;
    const int gyC = y0 + 1;
    const int gyD = (y0 + 2 == H_) ? H_ - 2 : y0 + 2;
    const int myRowA = (ry == 0) ? gyA : gyC;   // staged row 2ry
    const int myRowB = (ry == 0) ? y0 : gyD;    // staged row 2ry+1

    const float* __restrict__ nb = nbrs + (size_t)(b * N_ + i) * C_ * HW_;
    const float* __restrict__ rp = ref + (size_t)b * C_ * HW_;
    const int offA = myRowA * W_ + x;
    const int offB = myRowB * W_ + x;
    const int offR = y * W_ + x;

    float dot[9];
#pragma unroll
    for (int k = 0; k < 9; ++k) dot[k] = 0.f;
    float nA = 0.f, nB = 0.f, r2 = 0.f;

    // ---- pass 1: dots + norms + ref2 ----
    float co0[CPB], co1[CPB], crf[CPB];
    float no0[CPB], no1[CPB], nrf[CPB];
#pragma unroll
    for (int u = 0; u < CPB; ++u) {
        const size_t co = (size_t)u * HW_;
        co0[u] = nb[co + offA]; co1[u] = nb[co + offB]; crf[u] = rp[co + offR];
    }
#pragma unroll 1
    for (int w = 0; w < NWIN; ++w) {
        const int base = (w & 1) * CPB;
#pragma unroll
        for (int u = 0; u < CPB; ++u) {
            s_own[base + u][2 * ry + 0][x] = co0[u];
            s_own[base + u][2 * ry + 1][x] = co1[u];
        }
        if (w + 1 < NWIN) {
#pragma unroll
            for (int u = 0; u < CPB; ++u) {
                const size_t co = (size_t)((w + 1) * CPB + u) * HW_;
                no0[u] = nb[co + offA]; no1[u] = nb[co + offB]; nrf[u] = rp[co + offR];
            }
        }
        __syncthreads();
#pragma unroll
        for (int u = 0; u < CPB; ++u) {
            const float w00 = s_own[base + u][ry + 0][xm], w02 = s_own[base + u][ry + 0][xp];
            const float w10 = s_own[base + u][ry + 1][xm], w12 = s_own[base + u][ry + 1][xp];
            const float w20 = s_own[base + u][ry + 2][xm], w22 = s_own[base + u][ry + 2][xp];
            float w01, w11, w21;
            if (ry == 0) { w01 = co0[u]; w11 = co1[u]; w21 = s_own[base + u][2][x]; }
            else         { w01 = s_own[base + u][1][x]; w11 = co0[u]; w21 = co1[u]; }
            const float rf = crf[u];
            nA += co0[u] * co0[u]; nB += co1[u] * co1[u]; r2 += rf * rf;
            dot[0] += rf * w00; dot[1] += rf * w01; dot[2] += rf * w02;
            dot[3] += rf * w10; dot[4] += rf * w11; dot[5] += rf * w12;
            dot[6] += rf * w20; dot[7] += rf * w21; dot[8] += rf * w22;
        }
#pragma unroll
        for (int u = 0; u < CPB; ++u) { co0[u] = no0[u]; co1[u] = no1[u]; crf[u] = nrf[u]; }
    }

    // ---- share norms, softmax in-register ----
    s_nrm[2 * ry + 0][x] = nA;
    s_nrm[2 * ry + 1][x] = nB;
    __syncthreads();
    float nk[9];
    nk[0] = s_nrm[ry + 0][xm]; nk[1] = s_nrm[ry + 0][x]; nk[2] = s_nrm[ry + 0][xp];
    nk[3] = s_nrm[ry + 1][xm]; nk[4] = s_nrm[ry + 1][x]; nk[5] = s_nrm[ry + 1][xp];
    nk[6] = s_nrm[ry + 2][xm]; nk[7] = s_nrm[ry + 2][x]; nk[8] = s_nrm[ry + 2][xp];

    const float invr = rsqrtf(fmaxf(r2, 1e-24f));
    float inv[9], d[9];
#pragma unroll
    for (int k = 0; k < 9; ++k) {
        inv[k] = rsqrtf(fmaxf(nk[k], 1e-24f));
        d[k] = dot[k] * invr * inv[k];
    }
    float mx = d[0];
#pragma unroll
    for (int k = 1; k < 9; ++k) mx = fmaxf(mx, d[k]);
    float ssum = 0.f;
#pragma unroll
    for (int k = 0; k < 9; ++k) { d[k] = __expf(d[k] - mx); ssum += d[k]; }
    const float is = 1.f / ssum;
    float wtp[9];
#pragma unroll
    for (int k = 0; k < 9; ++k) wtp[k] = d[k] * is * inv[k];

    // ---- pass 2: aggregate + wdiff + store ----
    const float* __restrict__ pm0 = nbrs + (size_t)(b * N_ + ((i + 1) & 3)) * C_ * HW_;
    const float* __restrict__ pm1 = nbrs + (size_t)(b * N_ + ((i + 2) & 3)) * C_ * HW_;
    const float* __restrict__ pm2 = nbrs + (size_t)(b * N_ + ((i + 3) & 3)) * C_ * HW_;
    float* __restrict__ op = out + (size_t)(b * 5 + i) * C_ * HW_ + offR;

    float q0c[CPB], q1c[CPB], q2c[CPB];
    float q0n[CPB], q1n[CPB], q2n[CPB];
#pragma unroll
    for (int u = 0; u < CPB; ++u) {
        const size_t co = (size_t)u * HW_;
        co0[u] = nb[co + offA]; co1[u] = nb[co + offB];
        q0c[u] = pm0[co + offR]; q1c[u] = pm1[co + offR]; q2c[u] = pm2[co + offR];
    }
#pragma unroll 1
    for (int w = 0; w < NWIN; ++w) {
        const int base = (w & 1) * CPB;
#pragma unroll
        for (int u = 0; u < CPB; ++u) {
            s_own[base + u][2 * ry + 0][x] = co0[u];
            s_own[base + u][2 * ry + 1][x] = co1[u];
        }
        if (w + 1 < NWIN) {
#pragma unroll
            for (int u = 0; u < CPB; ++u) {
                const size_t co = (size_t)((w + 1) * CPB + u) * HW_;
                no0[u] = nb[co + offA]; no1[u] = nb[co + offB];
                q0n[u] = pm0[co + offR]; q1n[u] = pm1[co + offR]; q2n[u] = pm2[co + offR];
            }
        }
        __syncthreads();
#pragma unroll
        for (int u = 0; u < CPB; ++u) {
            const float w00 = s_own[base + u][ry + 0][xm], w02 = s_own[base + u][ry + 0][xp];
            const float w10 = s_own[base + u][ry + 1][xm], w12 = s_own[base + u][ry + 1][xp];
            const float w20 = s_own[base + u][ry + 2][xm], w22 = s_own[base + u][ry + 2][xp];
            float w01, w11, w21;
            if (ry == 0) { w01 = co0[u]; w11 = co1[u]; w21 = s_own[base + u][2][x]; }
            else         { w01 = s_own[base + u][1][x]; w11 = co0[u]; w21 = co1[u]; }
            const float agg = wtp[0] * w00 + wtp[1] * w01 + wtp[2] * w02
                            + wtp[3] * w10 + wtp[4] * w11 + wtp[5] * w12
                            + wtp[6] * w20 + wtp[7] * w21 + wtp[8] * w22;
            const float ctr = w11;
            const float dd = ctr - 0.25f * (ctr + q0c[u] + q1c[u] + q2c[u]);
            op[(size_t)(w * CPB + u) * HW_] = agg * __expf(-dd * dd);
        }
#pragma unroll
        for (int u = 0; u < CPB; ++u) {
            co0[u] = no0[u]; co1[u] = no1[u];
            q0c[u] = q0n[u]; q1c[u] = q1n[u]; q2c[u] = q2n[u];
        }
    }
}

}  // namespace

extern "C" void kernel_launch(void* const* d_in, const int* in_sizes, int n_in,
                              void* d_out, int out_size, void* d_ws, size_t ws_size,
                              hipStream_t stream) {
    const float* nbrs = (const float*)d_in[0];
    const float* ref = (const float*)d_in[1];
    float* out = (float*)d_out;

    // slot 4 = ref copy
    copyref_kernel<<<(B_ * C_ * HW_ / 4) / 256, 256, 0, stream>>>(ref, out);

    // main: B*N*(H/2) = 1024 two-row blocks of 256 threads
    localcorr_kernel<<<B_ * N_ * (H_ / 2), 256, 0, stream>>>(nbrs, ref, out);
}